// Round 11
// baseline (441.802 us; speedup 1.0000x reference)
//
#include <hip/hip_runtime.h>
#include <hip/hip_cooperative_groups.h>

#define D_IN 128
#define HID 256
#define BKT_SHIFT 8
#define BKT_SIZE 256        // nodes per bucket; pack (src<<8)|(dst&255), src<2^16
#define BKT_CAP 10240       // fixed edge capacity per bucket (mean ~8192, +22 sigma)
#define CHUNK 4096          // edges per chunk in binning phase
#define PAD_SLACK 2048      // per-bucket csr slack >= max pad (7*256=1792)
#define LSTR 264            // LDS row stride (bf16) for h tile
#define ASTR 136            // LDS row stride (bf16) for A tile

typedef __attribute__((ext_vector_type(8))) short short8;   // 8 bf16 MFMA A/B frag
typedef __attribute__((ext_vector_type(4))) float floatx4;  // MFMA C/D frag
typedef __attribute__((ext_vector_type(4))) int intx4;

// fp32 -> bf16 (RNE), branch-free; inputs finite
static __device__ __forceinline__ unsigned short f2b(float f) {
  unsigned u = __float_as_uint(f);
  unsigned r = (u + 0x7fffu + ((u >> 16) & 1u)) >> 16;
  return (unsigned short)r;
}

static __device__ __forceinline__ void unpack8(uint4 v, float* f) {
  f[0] = __uint_as_float(v.x << 16); f[1] = __uint_as_float(v.x & 0xffff0000u);
  f[2] = __uint_as_float(v.y << 16); f[3] = __uint_as_float(v.y & 0xffff0000u);
  f[4] = __uint_as_float(v.z << 16); f[5] = __uint_as_float(v.z & 0xffff0000u);
  f[6] = __uint_as_float(v.w << 16); f[7] = __uint_as_float(v.w & 0xffff0000u);
}

static __device__ __forceinline__ void acc_fma(float* acc, uint4 v, float w) {
  float g[8];
  unpack8(v, g);
#pragma unroll
  for (int d = 0; d < 8; ++d) acc[d] = fmaf(g[d], w, acc[d]);
}

// R5-proven unroll-8 gather with one-iteration csr prefetch.
static __device__ __forceinline__ void gather_row(float* acc, const uint4* __restrict__ Hq,
                                                  const float* __restrict__ dinv,
                                                  const int* __restrict__ csr,
                                                  int2 se, float dv, int lane) {
  intx4 c0 = *(const intx4*)(csr + se.x);
  intx4 c1 = *(const intx4*)(csr + se.x + 4);
  for (int j = se.x; j < se.y; ) {
    const int jn = j + 8;
    const int jp = (jn < se.y) ? jn : se.x;  // clamp: last-iter prefetch unused
    intx4 n0 = *(const intx4*)(csr + jp);
    intx4 n1 = *(const intx4*)(csr + jp + 4);
    float w0 = dinv[c0.x] * dv, w1 = dinv[c0.y] * dv;
    float w2 = dinv[c0.z] * dv, w3 = dinv[c0.w] * dv;
    float w4 = dinv[c1.x] * dv, w5 = dinv[c1.y] * dv;
    float w6 = dinv[c1.z] * dv, w7 = dinv[c1.w] * dv;
    uint4 v0 = Hq[(size_t)c0.x * 16 + lane];
    uint4 v1 = Hq[(size_t)c0.y * 16 + lane];
    uint4 v2 = Hq[(size_t)c0.z * 16 + lane];
    uint4 v3 = Hq[(size_t)c0.w * 16 + lane];
    uint4 v4 = Hq[(size_t)c1.x * 16 + lane];
    uint4 v5 = Hq[(size_t)c1.y * 16 + lane];
    uint4 v6 = Hq[(size_t)c1.z * 16 + lane];
    uint4 v7 = Hq[(size_t)c1.w * 16 + lane];
    acc_fma(acc, v0, w0);
    acc_fma(acc, v1, w1);
    acc_fma(acc, v2, w2);
    acc_fma(acc, v3, w3);
    acc_fma(acc, v4, w4);
    acc_fma(acc, v5, w5);
    acc_fma(acc, v6, w6);
    acc_fma(acc, v7, w7);
    c0 = n0; c1 = n1; j = jn;
  }
}

// ====== K1 (cooperative): cursor-zero -> bin-scatter + conversions -> bucket build ======
// 256 threads (R9-proven contention level), ~2KB LDS, low VGPR — all three phases
// share the same cheap config, so R10's config-coupling problem doesn't apply.
// grid.sync() replaces the memset dispatch + 2 kernel boundaries.

__global__ __launch_bounds__(256) void coop_front_build(
    const int* __restrict__ src, const int* __restrict__ dst,
    int* __restrict__ bkt_cursor, int* __restrict__ ebuf,
    const float4* __restrict__ x4, unsigned short* __restrict__ xb,
    const float* __restrict__ W1, unsigned short* __restrict__ Wt1,
    const float* __restrict__ W2, unsigned short* __restrict__ Wt2,
    float* __restrict__ dinv, int2* __restrict__ rowse, int* __restrict__ csr,
    unsigned short* __restrict__ tb,
    int E, int N, int nbkt, int nchunk, int n4) {
  namespace cg = cooperative_groups;
  cg::grid_group gg = cg::this_grid();

  __shared__ union {
    struct { int hist[BKT_SIZE]; int bbase[BKT_SIZE]; } p1;
    struct { int hist[BKT_SIZE]; int srs[BKT_SIZE]; int wsums[4]; } p2;
  } sm;

  const int bid = blockIdx.x, tid = threadIdx.x;
  const int gdim = gridDim.x;
  const int gtid = bid * 256 + tid;
  const int gstr = gdim * 256;

  // ---- P0: zero relative bucket cursors ----
  for (int i = gtid; i < nbkt; i += gstr) bkt_cursor[i] = 0;
  gg.sync();

  // ---- P1: bin-scatter chunks; then conversions + sentinels (grid-stride) ----
  for (int vb = bid; vb < nchunk; vb += gdim) {
    if (tid < nbkt) sm.p1.hist[tid] = 0;
    __syncthreads();
    const int base = vb * CHUNK;
    const int end = min(base + CHUNK, E);
    for (int e = base + tid; e < end; e += 256)
      atomicAdd(&sm.p1.hist[dst[e] >> BKT_SHIFT], 1);
    __syncthreads();
    if (tid < nbkt) {
      int c = sm.p1.hist[tid];
      sm.p1.bbase[tid] = c > 0 ? atomicAdd(&bkt_cursor[tid], c) : 0;  // relative base
      sm.p1.hist[tid] = 0;  // reuse as intra-block cursor
    }
    __syncthreads();
    for (int e = base + tid; e < end; e += 256) {
      int d = dst[e];
      int b = d >> BKT_SHIFT;
      int off = atomicAdd(&sm.p1.hist[b], 1);
      int rel = sm.p1.bbase[b] + off;
      if (rel < BKT_CAP)  // capacity guard (never trips for uniform input)
        ebuf[b * BKT_CAP + rel] = (src[e] << BKT_SHIFT) | (d & (BKT_SIZE - 1));
    }
    __syncthreads();  // hist reused next vb
  }
  // x (fp32) -> xb (bf16)
  for (int i = gtid; i < n4; i += gstr) {
    float4 v = x4[i];
    ushort4 o;
    o.x = f2b(v.x); o.y = f2b(v.y); o.z = f2b(v.z); o.w = f2b(v.w);
    *(ushort4*)(xb + (size_t)i * 4) = o;
  }
  // W1[128][256] -> Wt1[256][128]
  for (int e = gtid; e < D_IN * HID; e += gstr)
    Wt1[(size_t)(e & 255) * D_IN + (e >> 8)] = f2b(W1[e]);
  // W2[256][128] -> Wt2[128][256]
  for (int e = gtid; e < HID * D_IN; e += gstr)
    Wt2[(size_t)(e & 127) * HID + (e >> 7)] = f2b(W2[e]);
  // sentinels: dinv[N]=0; zero row N of xb/tb (gathered with weight 0)
  if (gtid == 0) dinv[N] = 0.f;
  if (gtid < 64)       ((unsigned*)(xb + (size_t)N * D_IN))[gtid]      = 0u;
  else if (gtid < 128) ((unsigned*)(tb + (size_t)N * D_IN))[gtid - 64] = 0u;
  gg.sync();

  // ---- P2: per-bucket degree hist -> dinv + rowse; padded CSR (R9 build body) ----
  for (int vb = bid; vb < nbkt; vb += gdim) {
    const int node0 = vb << BKT_SHIFT;
    const int nloc = min(BKT_SIZE, N - node0);
    const int ebeg = vb * BKT_CAP;
    const int eend = ebeg + min(bkt_cursor[vb], BKT_CAP);
    sm.p2.hist[tid] = 0;
    __syncthreads();
    for (int e = ebeg + tid; e < eend; e += 256)
      atomicAdd(&sm.p2.hist[ebuf[e] & (BKT_SIZE - 1)], 1);
    __syncthreads();
    const int h = sm.p2.hist[tid];
    const int p = (h + 7) & ~7;
    const int lane = tid & 63, wid = tid >> 6;
    int incl = p;
#pragma unroll
    for (int off = 1; off < 64; off <<= 1) {
      int t = __shfl_up(incl, off);
      if (lane >= off) incl += t;
    }
    if (lane == 63) sm.p2.wsums[wid] = incl;
    __syncthreads();
    int wex = 0;
    for (int w = 0; w < wid; ++w) wex += sm.p2.wsums[w];
    const int ex = wex + incl - p;
    if (tid < nloc) {
      int st = vb * (BKT_CAP + PAD_SLACK) + ex;
      dinv[node0 + tid] = rsqrtf((float)(h + 1));
      rowse[node0 + tid] = make_int2(st, st + p);
      sm.p2.srs[tid] = st;
    }
    __syncthreads();  // srs written before cursor reuse below reads it
    sm.p2.hist[tid] = 0;  // reuse as per-node cursors
    __syncthreads();
    for (int e = ebeg + tid; e < eend; e += 256) {
      int u = ebuf[e];
      int l = u & (BKT_SIZE - 1);
      int pos = atomicAdd(&sm.p2.hist[l], 1);
      csr[sm.p2.srs[l] + pos] = u >> BKT_SHIFT;
    }
    __syncthreads();
    for (int l = tid; l < nloc; l += 256) {
      int deg = sm.p2.hist[l];
      int pp = (deg + 7) & ~7;
      int s0 = sm.p2.srs[l];
      for (int q = s0 + deg; q < s0 + pp; ++q) csr[q] = N;  // sentinel: dinv[N]=0
    }
    __syncthreads();
  }
}

// ========== K2 (R9-exact): agg1 (Â x) -> LDS A-tile -> gemm12 -> tb ==========
// 512 threads = 8 waves, 32 nodes/block; __launch_bounds__(512,4) (VGPR cap 128,
// natural ~52, no spill — R8/R9 lessons).

__global__ __launch_bounds__(512, 4) void agg1_gemm_kernel(
    const uint4* __restrict__ Hq, const int2* __restrict__ rowse,
    const int* __restrict__ csr, const float* __restrict__ dinv,
    const unsigned short* __restrict__ Wt1, const float* __restrict__ b1,
    const unsigned short* __restrict__ Wt2, unsigned short* __restrict__ T, int M) {
  __shared__ unsigned short as_[32][ASTR];  // Â x tile (bf16)
  __shared__ unsigned short hs[32][LSTR];   // h tile (bf16)
  const int tid = threadIdx.x;
  const int node0 = blockIdx.x * 32;

  // ---- agg phase: 32 nodes x 16 lanes ----
  {
    const int glane = tid & 15;
    const int lrow = tid >> 4;  // 0..31
    const int node = node0 + lrow;
    float acc[8] = {0.f, 0.f, 0.f, 0.f, 0.f, 0.f, 0.f, 0.f};
    if (node < M) {
      const float dv = dinv[node];
      uint4 sv = Hq[(size_t)node * 16 + glane];
      float f[8];
      unpack8(sv, f);
      const float ws = dv * dv;
#pragma unroll
      for (int d = 0; d < 8; ++d) acc[d] = f[d] * ws;
      gather_row(acc, Hq, dinv, csr, rowse[node], dv, glane);
    }
    uint4 o;
    o.x = (unsigned)f2b(acc[0]) | ((unsigned)f2b(acc[1]) << 16);
    o.y = (unsigned)f2b(acc[2]) | ((unsigned)f2b(acc[3]) << 16);
    o.z = (unsigned)f2b(acc[4]) | ((unsigned)f2b(acc[5]) << 16);
    o.w = (unsigned)f2b(acc[6]) | ((unsigned)f2b(acc[7]) << 16);
    *(uint4*)&as_[lrow][glane * 8] = o;  // feature c at as_[row][c]
  }
  __syncthreads();

  // ---- gemm phase (8-wave column split) ----
  const int wave = tid >> 6;  // 0..7
  const int lane = tid & 63;
  const int quad = lane >> 4;
  const int l16 = lane & 15;

  // phase 1: hs[0..31][wave*32 .. +32) = relu(as_ @ W1 + b1)
  const short8* bp1 = (const short8*)(Wt1 + (size_t)(wave * 32 + l16) * D_IN + quad * 8);
  floatx4 acc1[2][2];  // [row-group][col-tile]
#pragma unroll
  for (int g = 0; g < 2; ++g)
#pragma unroll
    for (int t = 0; t < 2; ++t) acc1[g][t] = floatx4{0.f, 0.f, 0.f, 0.f};

#pragma unroll
  for (int kt = 0; kt < 4; ++kt) {  // K = 128
    short8 a0 = *(const short8*)&as_[0 * 16 + l16][kt * 32 + quad * 8];
    short8 a1 = *(const short8*)&as_[1 * 16 + l16][kt * 32 + quad * 8];
#pragma unroll
    for (int t = 0; t < 2; ++t) {
      short8 b = bp1[kt * 4 + t * 256];  // t*16 rows * 16 short8/row
      acc1[0][t] = __builtin_amdgcn_mfma_f32_16x16x32_bf16(a0, b, acc1[0][t], 0, 0, 0);
      acc1[1][t] = __builtin_amdgcn_mfma_f32_16x16x32_bf16(a1, b, acc1[1][t], 0, 0, 0);
    }
  }
#pragma unroll
  for (int t = 0; t < 2; ++t) {
    const float bv = b1[wave * 32 + t * 16 + l16];
#pragma unroll
    for (int g = 0; g < 2; ++g)
#pragma unroll
      for (int r = 0; r < 4; ++r) {
        float v = acc1[g][t][r] + bv;
        v = v > 0.f ? v : 0.f;
        hs[g * 16 + quad * 4 + r][wave * 32 + t * 16 + l16] = f2b(v);
      }
  }
  __syncthreads();

  // phase 2: t[0..31][wave*16 .. +16) = hs @ Wt2^T
  const short8* bp2 = (const short8*)(Wt2 + (size_t)(wave * 16 + l16) * HID + quad * 8);
  floatx4 acc2[2];
#pragma unroll
  for (int g = 0; g < 2; ++g) acc2[g] = floatx4{0.f, 0.f, 0.f, 0.f};

#pragma unroll
  for (int kt = 0; kt < 8; ++kt) {  // K = 256
    short8 a0 = *(const short8*)&hs[0 * 16 + l16][kt * 32 + quad * 8];
    short8 a1 = *(const short8*)&hs[1 * 16 + l16][kt * 32 + quad * 8];
    short8 b = bp2[kt * 4];
    acc2[0] = __builtin_amdgcn_mfma_f32_16x16x32_bf16(a0, b, acc2[0], 0, 0, 0);
    acc2[1] = __builtin_amdgcn_mfma_f32_16x16x32_bf16(a1, b, acc2[1], 0, 0, 0);
  }
  __syncthreads();  // all waves done reading hs before overwrite

  // t-tile -> LDS (cols wave*16..+16)
#pragma unroll
  for (int g = 0; g < 2; ++g)
#pragma unroll
    for (int r = 0; r < 4; ++r)
      hs[g * 16 + quad * 4 + r][wave * 16 + l16] = f2b(acc2[g][r]);
  __syncthreads();

  // coalesced store: 32 rows x 128 cols bf16; 512 threads x 16B
  {
    const int r = tid >> 4;
    const int c = (tid & 15) * 8;
    const int row = node0 + r;
    uint4 v = *(const uint4*)&hs[r][c];
    if (row < M) *(uint4*)&T[(size_t)row * D_IN + c] = v;
  }
}

// ========== K3 (R9-exact): agg2 (Â tb + skip + bias), unroll-8, 48 VGPR ==========

__global__ __launch_bounds__(256) void agg2_kernel(const uint4* __restrict__ Hq,
                                                   const int2* __restrict__ rowse,
                                                   const int* __restrict__ csr,
                                                   const float* __restrict__ dinv,
                                                   const float* __restrict__ skip,
                                                   const float* __restrict__ bias,
                                                   float* __restrict__ OUT, int n) {
  const int lane = threadIdx.x & 15;
  const int node = blockIdx.x * 16 + (threadIdx.x >> 4);
  if (node >= n) return;

  const float dv = dinv[node];
  float acc[8];
  {
    uint4 sv = Hq[(size_t)node * 16 + lane];
    float f[8];
    unpack8(sv, f);
    const float ws = dv * dv;
#pragma unroll
    for (int d = 0; d < 8; ++d) acc[d] = f[d] * ws;
  }
  gather_row(acc, Hq, dinv, csr, rowse[node], dv, lane);

  const float* sp = skip + (size_t)node * 128 + lane * 8;
  const float* bp = bias + lane * 8;
  float4 s0 = *(const float4*)sp, s1 = *(const float4*)(sp + 4);
  float4 b0 = *(const float4*)bp, b1 = *(const float4*)(bp + 4);
  float* op = OUT + (size_t)node * 128 + lane * 8;
  *(float4*)op = make_float4(acc[0] + s0.x + b0.x, acc[1] + s0.y + b0.y,
                             acc[2] + s0.z + b0.z, acc[3] + s0.w + b0.w);
  *(float4*)(op + 4) = make_float4(acc[4] + s1.x + b1.x, acc[5] + s1.y + b1.y,
                                   acc[6] + s1.z + b1.z, acc[7] + s1.w + b1.w);
}

// ================= launch =================

extern "C" void kernel_launch(void* const* d_in, const int* in_sizes, int n_in,
                              void* d_out, int out_size, void* d_ws, size_t ws_size,
                              hipStream_t stream) {
  const float* x  = (const float*)d_in[0];
  const int*   ei = (const int*)d_in[1];
  const float* W1 = (const float*)d_in[2];
  const float* b1 = (const float*)d_in[3];
  const float* W2 = (const float*)d_in[4];
  const float* b2 = (const float*)d_in[5];
  float* out = (float*)d_out;

  const int N = in_sizes[0] / D_IN;      // requires N <= 65536 (packed ebuf)
  const int E = in_sizes[1] / 2;
  const int* srcA = ei;
  const int* dstA = ei + E;
  const int NBKT = (N + BKT_SIZE - 1) >> BKT_SHIFT;  // 196 for N=50000
  const int NCHUNK = (E + CHUNK - 1) / CHUNK;        // 391
  const int n4 = N * D_IN / 4;

  // ---- workspace (256B aligned) ----
  char* ws = (char*)d_ws;
  size_t off = 0;
  auto alloc = [&](size_t bytes) { void* p = ws + off; off = (off + bytes + 255) & ~(size_t)255; return p; };
  int*            bkt_cursor = (int*)           alloc((size_t)NBKT * 4);
  float*          dinv       = (float*)         alloc((size_t)(N + 1) * 4);  // +sentinel
  int2*           rowse      = (int2*)          alloc((size_t)N * 8);
  int*            ebuf       = (int*)           alloc((size_t)NBKT * BKT_CAP * 4);
  int*            csr        = (int*)           alloc((size_t)NBKT * (BKT_CAP + PAD_SLACK) * 4);
  unsigned short* xb         = (unsigned short*)alloc((size_t)(N + 1) * D_IN * 2);
  unsigned short* tb         = (unsigned short*)alloc((size_t)(N + 1) * D_IN * 2);
  unsigned short* Wt1        = (unsigned short*)alloc((size_t)D_IN * HID * 2);
  unsigned short* Wt2        = (unsigned short*)alloc((size_t)D_IN * HID * 2);

  // cooperative grid for K1 (static-cached host-only queries; R10-proven pattern)
  static int coopGrid = 0;
  if (coopGrid == 0) {
    int dev = 0;
    (void)hipGetDevice(&dev);
    hipDeviceProp_t prop;
    (void)hipGetDeviceProperties(&prop, dev);
    int nb = 0;
    (void)hipOccupancyMaxActiveBlocksPerMultiprocessor(&nb, coop_front_build, 256, 0);
    if (nb < 1) nb = 1;
    coopGrid = nb * prop.multiProcessorCount;
    if (coopGrid < 1) coopGrid = 256;
    if (coopGrid > 1024) coopGrid = 1024;  // covers 391 chunks + conversions amply
  }

  // 1) K1 (cooperative): cursors -> scatter+convert -> build   (replaces 3 dispatches)
  {
    void* args[] = {
        (void*)&srcA, (void*)&dstA, (void*)&bkt_cursor, (void*)&ebuf,
        (void*)&x,    (void*)&xb,   (void*)&W1, (void*)&Wt1, (void*)&W2, (void*)&Wt2,
        (void*)&dinv, (void*)&rowse, (void*)&csr, (void*)&tb,
        (void*)&E, (void*)&N, (void*)&NBKT, (void*)&NCHUNK, (void*)&n4};
    (void)hipLaunchCooperativeKernel((void*)coop_front_build, dim3(coopGrid), dim3(256),
                                     args, 0, stream);
  }
  // 2) K2: tb = relu((Â x) @ W1 + b1) @ W2   (R9-exact)
  agg1_gemm_kernel<<<(N + 31) / 32, 512, 0, stream>>>((const uint4*)xb, rowse, csr, dinv,
                                                      Wt1, b1, Wt2, tb, N);
  // 3) K3: out = Â tb + x + b2   (R9-exact)
  agg2_kernel<<<(N + 15) / 16, 256, 0, stream>>>((const uint4*)tb, rowse, csr,
                                                 dinv, x, b2, out, N);
}

// Round 12
// 267.188 us; speedup vs baseline: 1.6535x; 1.6535x over previous
//
#include <hip/hip_runtime.h>

#define D_IN 128
#define HID 256
#define BKT_SHIFT 6
#define BKT_SIZE 64         // nodes per bucket; pack (src<<6)|(dst&63), src<2^16
#define BKT_CAP 3072        // fixed edge capacity per bucket (mean ~2048, +22 sigma)
#define NBKT_MAX 1024       // N <= 65536 -> nbkt <= 1024 (front LDS bound)
#define CHUNK 4096          // edges per chunk in binning phase
#define PAD_SLACK 512       // per-bucket csr slack >= max pad (7*64=448)
#define LSTR 264            // LDS row stride (bf16) for h tile
#define ASTR 136            // LDS row stride (bf16) for A tile

typedef __attribute__((ext_vector_type(8))) short short8;   // 8 bf16 MFMA A/B frag
typedef __attribute__((ext_vector_type(4))) float floatx4;  // MFMA C/D frag
typedef __attribute__((ext_vector_type(4))) int intx4;

// fp32 -> bf16 (RNE), branch-free; inputs finite
static __device__ __forceinline__ unsigned short f2b(float f) {
  unsigned u = __float_as_uint(f);
  unsigned r = (u + 0x7fffu + ((u >> 16) & 1u)) >> 16;
  return (unsigned short)r;
}

static __device__ __forceinline__ void unpack8(uint4 v, float* f) {
  f[0] = __uint_as_float(v.x << 16); f[1] = __uint_as_float(v.x & 0xffff0000u);
  f[2] = __uint_as_float(v.y << 16); f[3] = __uint_as_float(v.y & 0xffff0000u);
  f[4] = __uint_as_float(v.z << 16); f[5] = __uint_as_float(v.z & 0xffff0000u);
  f[6] = __uint_as_float(v.w << 16); f[7] = __uint_as_float(v.w & 0xffff0000u);
}

static __device__ __forceinline__ void acc_fma(float* acc, uint4 v, float w) {
  float g[8];
  unpack8(v, g);
#pragma unroll
  for (int d = 0; d < 8; ++d) acc[d] = fmaf(g[d], w, acc[d]);
}

// R5-proven unroll-8 gather with one-iteration csr prefetch.
static __device__ __forceinline__ void gather_row(float* acc, const uint4* __restrict__ Hq,
                                                  const float* __restrict__ dinv,
                                                  const int* __restrict__ csr,
                                                  int2 se, float dv, int lane) {
  intx4 c0 = *(const intx4*)(csr + se.x);
  intx4 c1 = *(const intx4*)(csr + se.x + 4);
  for (int j = se.x; j < se.y; ) {
    const int jn = j + 8;
    const int jp = (jn < se.y) ? jn : se.x;  // clamp: last-iter prefetch unused
    intx4 n0 = *(const intx4*)(csr + jp);
    intx4 n1 = *(const intx4*)(csr + jp + 4);
    float w0 = dinv[c0.x] * dv, w1 = dinv[c0.y] * dv;
    float w2 = dinv[c0.z] * dv, w3 = dinv[c0.w] * dv;
    float w4 = dinv[c1.x] * dv, w5 = dinv[c1.y] * dv;
    float w6 = dinv[c1.z] * dv, w7 = dinv[c1.w] * dv;
    uint4 v0 = Hq[(size_t)c0.x * 16 + lane];
    uint4 v1 = Hq[(size_t)c0.y * 16 + lane];
    uint4 v2 = Hq[(size_t)c0.z * 16 + lane];
    uint4 v3 = Hq[(size_t)c0.w * 16 + lane];
    uint4 v4 = Hq[(size_t)c1.x * 16 + lane];
    uint4 v5 = Hq[(size_t)c1.y * 16 + lane];
    uint4 v6 = Hq[(size_t)c1.z * 16 + lane];
    uint4 v7 = Hq[(size_t)c1.w * 16 + lane];
    acc_fma(acc, v0, w0);
    acc_fma(acc, v1, w1);
    acc_fma(acc, v2, w2);
    acc_fma(acc, v3, w3);
    acc_fma(acc, v4, w4);
    acc_fma(acc, v5, w5);
    acc_fma(acc, v6, w6);
    acc_fma(acc, v7, w7);
    c0 = n0; c1 = n1; j = jn;
  }
}

// ========== K1 (fused): bin_scatter + x->bf16 + W transposes + sentinels ==========
// R9 structure; histogram generalized to nbkt (<=1024) entries with strided loops.

__global__ __launch_bounds__(256) void fused_front_kernel(
    const int* __restrict__ src, const int* __restrict__ dst,
    int* __restrict__ bkt_cursor, int* __restrict__ ebuf, int E, int nbkt, int nchunk,
    const float4* __restrict__ x4, unsigned short* __restrict__ xb, int n4,
    const float* __restrict__ W1, unsigned short* __restrict__ Wt1,
    const float* __restrict__ W2, unsigned short* __restrict__ Wt2,
    float* __restrict__ dinv, unsigned short* __restrict__ tb, int N) {
  const int bid = blockIdx.x;
  const int tid = threadIdx.x;
  if (bid < nchunk) {
    __shared__ int hist[NBKT_MAX];
    __shared__ int bbase[NBKT_MAX];
    for (int b = tid; b < nbkt; b += 256) hist[b] = 0;
    __syncthreads();
    const int base = bid * CHUNK;
    const int end = min(base + CHUNK, E);
    for (int e = base + tid; e < end; e += 256)
      atomicAdd(&hist[dst[e] >> BKT_SHIFT], 1);
    __syncthreads();
    for (int b = tid; b < nbkt; b += 256) {
      int c = hist[b];
      bbase[b] = c > 0 ? atomicAdd(&bkt_cursor[b], c) : 0;  // relative base
      hist[b] = 0;  // reuse as intra-block cursor
    }
    __syncthreads();
    for (int e = base + tid; e < end; e += 256) {
      int d = dst[e];
      int b = d >> BKT_SHIFT;
      int off = atomicAdd(&hist[b], 1);
      int rel = bbase[b] + off;
      if (rel < BKT_CAP)  // capacity guard (never trips for uniform input)
        ebuf[b * BKT_CAP + rel] = (src[e] << BKT_SHIFT) | (d & (BKT_SIZE - 1));
    }
    return;
  }
  const int nxblk = (n4 + 255) / 256;
  if (bid < nchunk + nxblk) {
    int i = (bid - nchunk) * 256 + tid;
    if (i >= n4) return;
    float4 v = x4[i];
    ushort4 o;
    o.x = f2b(v.x); o.y = f2b(v.y); o.z = f2b(v.z); o.w = f2b(v.w);
    *(ushort4*)(xb + (size_t)i * 4) = o;
  } else if (bid < nchunk + nxblk + 128) {
    // W1[K=128][N=256] -> Wt1[N][K]
    int e = (bid - nchunk - nxblk) * 256 + tid;
    int k = e >> 8, n = e & 255;
    Wt1[(size_t)n * D_IN + k] = f2b(W1[e]);
  } else if (bid < nchunk + nxblk + 256) {
    // W2[K=256][N=128] -> Wt2[N][K]
    int e = (bid - nchunk - nxblk - 128) * 256 + tid;
    int k = e >> 7, n = e & 127;
    Wt2[(size_t)n * HID + k] = f2b(W2[e]);
  } else {
    // sentinels: dinv[N]=0; zero row N of xb/tb (gathered with weight 0)
    if (tid == 0) dinv[N] = 0.f;
    if (tid < 64)       ((unsigned*)(xb + (size_t)N * D_IN))[tid]      = 0u;
    else if (tid < 128) ((unsigned*)(tb + (size_t)N * D_IN))[tid - 64] = 0u;
  }
}

// ========== K2: per-bucket degree hist -> dinv + rowse; padded CSR ==========
// 64 nodes/bucket -> 782 blocks (~3/CU, 12 waves/CU) vs R9's 196 (0.77/CU):
// the LDS-atomic latency chains now overlap across blocks. Scan = 1-wave shfl.

__global__ __launch_bounds__(256) void bucket_build_kernel(const int* __restrict__ ebuf,
                                                           const int* __restrict__ bkt_cursor,
                                                           float* __restrict__ dinv,
                                                           int2* __restrict__ rowse,
                                                           int* __restrict__ csr,
                                                           int N, int nbkt) {
  __shared__ int hist[BKT_SIZE];
  __shared__ int srs[BKT_SIZE];
  const int b = blockIdx.x;
  const int tid = threadIdx.x;
  const int node0 = b << BKT_SHIFT;
  const int nloc = min(BKT_SIZE, N - node0);
  const int ebeg = b * BKT_CAP;
  const int eend = ebeg + min(bkt_cursor[b], BKT_CAP);

  if (tid < BKT_SIZE) hist[tid] = 0;
  __syncthreads();
  for (int e = ebeg + tid; e < eend; e += 256)
    atomicAdd(&hist[ebuf[e] & (BKT_SIZE - 1)], 1);
  __syncthreads();

  // padded (multiple-of-8) 64-wide exclusive scan: wave 0 only (tid==lane)
  if (tid < BKT_SIZE) {
    const int h = hist[tid];
    const int p = (h + 7) & ~7;
    int incl = p;
#pragma unroll
    for (int off = 1; off < 64; off <<= 1) {
      int t = __shfl_up(incl, off);
      if (tid >= off) incl += t;
    }
    const int ex = incl - p;
    if (tid < nloc) {
      int st = b * (BKT_CAP + PAD_SLACK) + ex;
      dinv[node0 + tid] = rsqrtf((float)(h + 1));
      rowse[node0 + tid] = make_int2(st, st + p);
      srs[tid] = st;
    }
  }
  __syncthreads();
  if (tid < BKT_SIZE) hist[tid] = 0;  // reuse as per-node cursors
  __syncthreads();

  for (int e = ebeg + tid; e < eend; e += 256) {
    int u = ebuf[e];
    int l = u & (BKT_SIZE - 1);
    int pos = atomicAdd(&hist[l], 1);
    csr[srs[l] + pos] = u >> BKT_SHIFT;
  }
  __syncthreads();
  for (int l = tid; l < nloc; l += 256) {
    int deg = hist[l];
    int pp = (deg + 7) & ~7;
    int s0 = srs[l];
    for (int q = s0 + deg; q < s0 + pp; ++q) csr[q] = N;  // sentinel: dinv[N]=0
  }
}

// ========== K3 (R9-exact): agg1 (Â x) -> LDS A-tile -> gemm12 -> tb ==========
// 512 threads = 8 waves, 32 nodes/block; __launch_bounds__(512,4) (VGPR cap 128,
// natural ~52, no spill — R8/R9 lessons).

__global__ __launch_bounds__(512, 4) void agg1_gemm_kernel(
    const uint4* __restrict__ Hq, const int2* __restrict__ rowse,
    const int* __restrict__ csr, const float* __restrict__ dinv,
    const unsigned short* __restrict__ Wt1, const float* __restrict__ b1,
    const unsigned short* __restrict__ Wt2, unsigned short* __restrict__ T, int M) {
  __shared__ unsigned short as_[32][ASTR];  // Â x tile (bf16)
  __shared__ unsigned short hs[32][LSTR];   // h tile (bf16)
  const int tid = threadIdx.x;
  const int node0 = blockIdx.x * 32;

  // ---- agg phase: 32 nodes x 16 lanes ----
  {
    const int glane = tid & 15;
    const int lrow = tid >> 4;  // 0..31
    const int node = node0 + lrow;
    float acc[8] = {0.f, 0.f, 0.f, 0.f, 0.f, 0.f, 0.f, 0.f};
    if (node < M) {
      const float dv = dinv[node];
      uint4 sv = Hq[(size_t)node * 16 + glane];
      float f[8];
      unpack8(sv, f);
      const float ws = dv * dv;
#pragma unroll
      for (int d = 0; d < 8; ++d) acc[d] = f[d] * ws;
      gather_row(acc, Hq, dinv, csr, rowse[node], dv, glane);
    }
    uint4 o;
    o.x = (unsigned)f2b(acc[0]) | ((unsigned)f2b(acc[1]) << 16);
    o.y = (unsigned)f2b(acc[2]) | ((unsigned)f2b(acc[3]) << 16);
    o.z = (unsigned)f2b(acc[4]) | ((unsigned)f2b(acc[5]) << 16);
    o.w = (unsigned)f2b(acc[6]) | ((unsigned)f2b(acc[7]) << 16);
    *(uint4*)&as_[lrow][glane * 8] = o;  // feature c at as_[row][c]
  }
  __syncthreads();

  // ---- gemm phase (8-wave column split) ----
  const int wave = tid >> 6;  // 0..7
  const int lane = tid & 63;
  const int quad = lane >> 4;
  const int l16 = lane & 15;

  // phase 1: hs[0..31][wave*32 .. +32) = relu(as_ @ W1 + b1)
  const short8* bp1 = (const short8*)(Wt1 + (size_t)(wave * 32 + l16) * D_IN + quad * 8);
  floatx4 acc1[2][2];  // [row-group][col-tile]
#pragma unroll
  for (int g = 0; g < 2; ++g)
#pragma unroll
    for (int t = 0; t < 2; ++t) acc1[g][t] = floatx4{0.f, 0.f, 0.f, 0.f};

#pragma unroll
  for (int kt = 0; kt < 4; ++kt) {  // K = 128
    short8 a0 = *(const short8*)&as_[0 * 16 + l16][kt * 32 + quad * 8];
    short8 a1 = *(const short8*)&as_[1 * 16 + l16][kt * 32 + quad * 8];
#pragma unroll
    for (int t = 0; t < 2; ++t) {
      short8 b = bp1[kt * 4 + t * 256];  // t*16 rows * 16 short8/row
      acc1[0][t] = __builtin_amdgcn_mfma_f32_16x16x32_bf16(a0, b, acc1[0][t], 0, 0, 0);
      acc1[1][t] = __builtin_amdgcn_mfma_f32_16x16x32_bf16(a1, b, acc1[1][t], 0, 0, 0);
    }
  }
#pragma unroll
  for (int t = 0; t < 2; ++t) {
    const float bv = b1[wave * 32 + t * 16 + l16];
#pragma unroll
    for (int g = 0; g < 2; ++g)
#pragma unroll
      for (int r = 0; r < 4; ++r) {
        float v = acc1[g][t][r] + bv;
        v = v > 0.f ? v : 0.f;
        hs[g * 16 + quad * 4 + r][wave * 32 + t * 16 + l16] = f2b(v);
      }
  }
  __syncthreads();

  // phase 2: t[0..31][wave*16 .. +16) = hs @ Wt2^T
  const short8* bp2 = (const short8*)(Wt2 + (size_t)(wave * 16 + l16) * HID + quad * 8);
  floatx4 acc2[2];
#pragma unroll
  for (int g = 0; g < 2; ++g) acc2[g] = floatx4{0.f, 0.f, 0.f, 0.f};

#pragma unroll
  for (int kt = 0; kt < 8; ++kt) {  // K = 256
    short8 a0 = *(const short8*)&hs[0 * 16 + l16][kt * 32 + quad * 8];
    short8 a1 = *(const short8*)&hs[1 * 16 + l16][kt * 32 + quad * 8];
    short8 b = bp2[kt * 4];
    acc2[0] = __builtin_amdgcn_mfma_f32_16x16x32_bf16(a0, b, acc2[0], 0, 0, 0);
    acc2[1] = __builtin_amdgcn_mfma_f32_16x16x32_bf16(a1, b, acc2[1], 0, 0, 0);
  }
  __syncthreads();  // all waves done reading hs before overwrite

  // t-tile -> LDS (cols wave*16..+16)
#pragma unroll
  for (int g = 0; g < 2; ++g)
#pragma unroll
    for (int r = 0; r < 4; ++r)
      hs[g * 16 + quad * 4 + r][wave * 16 + l16] = f2b(acc2[g][r]);
  __syncthreads();

  // coalesced store: 32 rows x 128 cols bf16; 512 threads x 16B
  {
    const int r = tid >> 4;
    const int c = (tid & 15) * 8;
    const int row = node0 + r;
    uint4 v = *(const uint4*)&hs[r][c];
    if (row < M) *(uint4*)&T[(size_t)row * D_IN + c] = v;
  }
}

// ========== K4 (R9-exact): agg2 (Â tb + skip + bias), unroll-8, 48 VGPR ==========

__global__ __launch_bounds__(256) void agg2_kernel(const uint4* __restrict__ Hq,
                                                   const int2* __restrict__ rowse,
                                                   const int* __restrict__ csr,
                                                   const float* __restrict__ dinv,
                                                   const float* __restrict__ skip,
                                                   const float* __restrict__ bias,
                                                   float* __restrict__ OUT, int n) {
  const int lane = threadIdx.x & 15;
  const int node = blockIdx.x * 16 + (threadIdx.x >> 4);
  if (node >= n) return;

  const float dv = dinv[node];
  float acc[8];
  {
    uint4 sv = Hq[(size_t)node * 16 + lane];
    float f[8];
    unpack8(sv, f);
    const float ws = dv * dv;
#pragma unroll
    for (int d = 0; d < 8; ++d) acc[d] = f[d] * ws;
  }
  gather_row(acc, Hq, dinv, csr, rowse[node], dv, lane);

  const float* sp = skip + (size_t)node * 128 + lane * 8;
  const float* bp = bias + lane * 8;
  float4 s0 = *(const float4*)sp, s1 = *(const float4*)(sp + 4);
  float4 b0 = *(const float4*)bp, b1 = *(const float4*)(bp + 4);
  float* op = OUT + (size_t)node * 128 + lane * 8;
  *(float4*)op = make_float4(acc[0] + s0.x + b0.x, acc[1] + s0.y + b0.y,
                             acc[2] + s0.z + b0.z, acc[3] + s0.w + b0.w);
  *(float4*)(op + 4) = make_float4(acc[4] + s1.x + b1.x, acc[5] + s1.y + b1.y,
                                   acc[6] + s1.z + b1.z, acc[7] + s1.w + b1.w);
}

// ================= launch =================

extern "C" void kernel_launch(void* const* d_in, const int* in_sizes, int n_in,
                              void* d_out, int out_size, void* d_ws, size_t ws_size,
                              hipStream_t stream) {
  const float* x  = (const float*)d_in[0];
  const int*   ei = (const int*)d_in[1];
  const float* W1 = (const float*)d_in[2];
  const float* b1 = (const float*)d_in[3];
  const float* W2 = (const float*)d_in[4];
  const float* b2 = (const float*)d_in[5];
  float* out = (float*)d_out;

  const int N = in_sizes[0] / D_IN;      // requires N <= 65536 (packed ebuf)
  const int E = in_sizes[1] / 2;
  const int* srcA = ei;
  const int* dstA = ei + E;
  const int NBKT = (N + BKT_SIZE - 1) >> BKT_SHIFT;  // 782 for N=50000
  const int NCHUNK = (E + CHUNK - 1) / CHUNK;        // 391
  const int n4 = N * D_IN / 4;

  // ---- workspace (256B aligned) ----
  char* ws = (char*)d_ws;
  size_t off = 0;
  auto alloc = [&](size_t bytes) { void* p = ws + off; off = (off + bytes + 255) & ~(size_t)255; return p; };
  int*            bkt_cursor = (int*)           alloc((size_t)NBKT * 4);
  float*          dinv       = (float*)         alloc((size_t)(N + 1) * 4);  // +sentinel
  int2*           rowse      = (int2*)          alloc((size_t)N * 8);
  int*            ebuf       = (int*)           alloc((size_t)NBKT * BKT_CAP * 4);
  int*            csr        = (int*)           alloc((size_t)NBKT * (BKT_CAP + PAD_SLACK) * 4);
  unsigned short* xb         = (unsigned short*)alloc((size_t)(N + 1) * D_IN * 2);
  unsigned short* tb         = (unsigned short*)alloc((size_t)(N + 1) * D_IN * 2);
  unsigned short* Wt1        = (unsigned short*)alloc((size_t)D_IN * HID * 2);
  unsigned short* Wt2        = (unsigned short*)alloc((size_t)D_IN * HID * 2);

  const int nxblk = (n4 + 255) / 256;

  // 1) zero relative bucket cursors
  (void)hipMemsetAsync(bkt_cursor, 0, (size_t)NBKT * 4, stream);
  // 2) K1: bin_scatter (low bids, starts first) + x->bf16 + W transposes + sentinels
  fused_front_kernel<<<NCHUNK + nxblk + 256 + 1, 256, 0, stream>>>(
      srcA, dstA, bkt_cursor, ebuf, E, NBKT, NCHUNK,
      (const float4*)x, xb, n4, W1, Wt1, W2, Wt2, dinv, tb, N);
  // 3) K2: per-bucket build (782 blocks, ~3/CU)
  bucket_build_kernel<<<NBKT, 256, 0, stream>>>(ebuf, bkt_cursor, dinv, rowse, csr, N, NBKT);
  // 4) K3: tb = relu((Â x) @ W1 + b1) @ W2   (R9-exact)
  agg1_gemm_kernel<<<(N + 31) / 32, 512, 0, stream>>>((const uint4*)xb, rowse, csr, dinv,
                                                      Wt1, b1, Wt2, tb, N);
  // 5) K4: out = Â tb + x + b2   (R9-exact)
  agg2_kernel<<<(N + 15) / 16, 256, 0, stream>>>((const uint4*)tb, rowse, csr,
                                                 dinv, x, b2, out, N);
}

// Round 13
// 262.412 us; speedup vs baseline: 1.6836x; 1.0182x over previous
//
#include <hip/hip_runtime.h>

#define D_IN 128
#define HID 256
#define BKT_SHIFT 6
#define BKT_SIZE 64         // nodes per bucket; pack (src<<6)|(dst&63), src<2^16
#define BKT_CAP 3072        // fixed edge capacity per bucket (mean ~2048, +22 sigma)
#define NBKT_MAX 1024       // N <= 65536 -> nbkt <= 1024 (front LDS bound)
#define CHUNK 4096          // edges per chunk in binning phase
#define PAD_SLACK 512       // per-bucket csr slack >= max pad (7*64=448)
#define LSTR 264            // LDS row stride (bf16) for h tile
#define ASTR 136            // LDS row stride (bf16) for A tile

typedef __attribute__((ext_vector_type(8))) short short8;   // 8 bf16 MFMA A/B frag
typedef __attribute__((ext_vector_type(4))) float floatx4;  // MFMA C/D frag
typedef __attribute__((ext_vector_type(4))) int intx4;

// fp32 -> bf16 (RNE), branch-free; inputs finite
static __device__ __forceinline__ unsigned short f2b(float f) {
  unsigned u = __float_as_uint(f);
  unsigned r = (u + 0x7fffu + ((u >> 16) & 1u)) >> 16;
  return (unsigned short)r;
}

static __device__ __forceinline__ void unpack8(uint4 v, float* f) {
  f[0] = __uint_as_float(v.x << 16); f[1] = __uint_as_float(v.x & 0xffff0000u);
  f[2] = __uint_as_float(v.y << 16); f[3] = __uint_as_float(v.y & 0xffff0000u);
  f[4] = __uint_as_float(v.z << 16); f[5] = __uint_as_float(v.z & 0xffff0000u);
  f[6] = __uint_as_float(v.w << 16); f[7] = __uint_as_float(v.w & 0xffff0000u);
}

static __device__ __forceinline__ void acc_add(float* acc, uint4 v) {
  float g[8];
  unpack8(v, g);
#pragma unroll
  for (int d = 0; d < 8; ++d) acc[d] += g[d];
}

// PRESCALED gather: acc += sum over row [se.x,se.y) of H_s[src] (H_s already
// carries dinv[src]; caller applies the x dv at the end). Per 8 edges: 2 csr
// loads + 8 uint4 gathers — the 8 random dinv loads of the weighted form are
// GONE (18 -> 10 vmem per iter). R5-proven one-iteration csr prefetch kept.
static __device__ __forceinline__ void gather_row(float* acc, const uint4* __restrict__ Hq,
                                                  const int* __restrict__ csr,
                                                  int2 se, int lane) {
  intx4 c0 = *(const intx4*)(csr + se.x);
  intx4 c1 = *(const intx4*)(csr + se.x + 4);
  for (int j = se.x; j < se.y; ) {
    const int jn = j + 8;
    const int jp = (jn < se.y) ? jn : se.x;  // clamp: last-iter prefetch unused
    intx4 n0 = *(const intx4*)(csr + jp);
    intx4 n1 = *(const intx4*)(csr + jp + 4);
    uint4 v0 = Hq[(size_t)c0.x * 16 + lane];
    uint4 v1 = Hq[(size_t)c0.y * 16 + lane];
    uint4 v2 = Hq[(size_t)c0.z * 16 + lane];
    uint4 v3 = Hq[(size_t)c0.w * 16 + lane];
    uint4 v4 = Hq[(size_t)c1.x * 16 + lane];
    uint4 v5 = Hq[(size_t)c1.y * 16 + lane];
    uint4 v6 = Hq[(size_t)c1.z * 16 + lane];
    uint4 v7 = Hq[(size_t)c1.w * 16 + lane];
    acc_add(acc, v0);
    acc_add(acc, v1);
    acc_add(acc, v2);
    acc_add(acc, v3);
    acc_add(acc, v4);
    acc_add(acc, v5);
    acc_add(acc, v6);
    acc_add(acc, v7);
    c0 = n0; c1 = n1; j = jn;
  }
}

// ========== K1 (fused): bin_scatter + W transposes + sentinels ==========
// x->xb conversion moved to bucket_build (needs dinv for prescale).

__global__ __launch_bounds__(256) void fused_front_kernel(
    const int* __restrict__ src, const int* __restrict__ dst,
    int* __restrict__ bkt_cursor, int* __restrict__ ebuf, int E, int nbkt, int nchunk,
    const float* __restrict__ W1, unsigned short* __restrict__ Wt1,
    const float* __restrict__ W2, unsigned short* __restrict__ Wt2,
    float* __restrict__ dinv, unsigned short* __restrict__ xb,
    unsigned short* __restrict__ tb, int N) {
  const int bid = blockIdx.x;
  const int tid = threadIdx.x;
  if (bid < nchunk) {
    __shared__ int hist[NBKT_MAX];
    __shared__ int bbase[NBKT_MAX];
    for (int b = tid; b < nbkt; b += 256) hist[b] = 0;
    __syncthreads();
    const int base = bid * CHUNK;
    const int end = min(base + CHUNK, E);
    for (int e = base + tid; e < end; e += 256)
      atomicAdd(&hist[dst[e] >> BKT_SHIFT], 1);
    __syncthreads();
    for (int b = tid; b < nbkt; b += 256) {
      int c = hist[b];
      bbase[b] = c > 0 ? atomicAdd(&bkt_cursor[b], c) : 0;  // relative base
      hist[b] = 0;  // reuse as intra-block cursor
    }
    __syncthreads();
    for (int e = base + tid; e < end; e += 256) {
      int d = dst[e];
      int b = d >> BKT_SHIFT;
      int off = atomicAdd(&hist[b], 1);
      int rel = bbase[b] + off;
      if (rel < BKT_CAP)  // capacity guard (never trips for uniform input)
        ebuf[b * BKT_CAP + rel] = (src[e] << BKT_SHIFT) | (d & (BKT_SIZE - 1));
    }
    return;
  }
  if (bid < nchunk + 128) {
    // W1[K=128][N=256] -> Wt1[N][K]
    int e = (bid - nchunk) * 256 + tid;
    int k = e >> 8, n = e & 255;
    Wt1[(size_t)n * D_IN + k] = f2b(W1[e]);
  } else if (bid < nchunk + 256) {
    // W2[K=256][N=128] -> Wt2[N][K]
    int e = (bid - nchunk - 128) * 256 + tid;
    int k = e >> 7, n = e & 127;
    Wt2[(size_t)n * HID + k] = f2b(W2[e]);
  } else {
    // sentinels: dinv[N]=0; zero row N of xb/tb (pad slots gather zero rows)
    if (tid == 0) dinv[N] = 0.f;
    if (tid < 64)       ((unsigned*)(xb + (size_t)N * D_IN))[tid]      = 0u;
    else if (tid < 128) ((unsigned*)(tb + (size_t)N * D_IN))[tid - 64] = 0u;
  }
}

// ========== K2: per-bucket degree hist -> dinv + rowse; padded CSR; x prescale ==========
// 64 nodes/bucket, 782 blocks. New: converts its 64 x rows to PRESCALED bf16
// (xb_s[n] = dinv[n]*x[n]) — the streaming work front lost, placed where dinv lives.

__global__ __launch_bounds__(256) void bucket_build_kernel(const int* __restrict__ ebuf,
                                                           const int* __restrict__ bkt_cursor,
                                                           const float4* __restrict__ x4,
                                                           unsigned short* __restrict__ xb,
                                                           float* __restrict__ dinv,
                                                           int2* __restrict__ rowse,
                                                           int* __restrict__ csr,
                                                           int N, int nbkt) {
  __shared__ int hist[BKT_SIZE];
  __shared__ int srs[BKT_SIZE];
  __shared__ float sdinv[BKT_SIZE];
  const int b = blockIdx.x;
  const int tid = threadIdx.x;
  const int node0 = b << BKT_SHIFT;
  const int nloc = min(BKT_SIZE, N - node0);
  const int ebeg = b * BKT_CAP;
  const int eend = ebeg + min(bkt_cursor[b], BKT_CAP);

  if (tid < BKT_SIZE) hist[tid] = 0;
  __syncthreads();
  for (int e = ebeg + tid; e < eend; e += 256)
    atomicAdd(&hist[ebuf[e] & (BKT_SIZE - 1)], 1);
  __syncthreads();

  // padded (multiple-of-8) 64-wide exclusive scan: wave 0 only (tid==lane)
  if (tid < BKT_SIZE) {
    const int h = hist[tid];
    const int p = (h + 7) & ~7;
    int incl = p;
#pragma unroll
    for (int off = 1; off < 64; off <<= 1) {
      int t = __shfl_up(incl, off);
      if (tid >= off) incl += t;
    }
    const int ex = incl - p;
    float dv = rsqrtf((float)(h + 1));
    sdinv[tid] = dv;
    if (tid < nloc) {
      int st = b * (BKT_CAP + PAD_SLACK) + ex;
      dinv[node0 + tid] = dv;
      rowse[node0 + tid] = make_int2(st, st + p);
      srs[tid] = st;
    }
  }
  __syncthreads();
  if (tid < BKT_SIZE) hist[tid] = 0;  // reuse as per-node cursors
  __syncthreads();

  for (int e = ebeg + tid; e < eend; e += 256) {
    int u = ebuf[e];
    int l = u & (BKT_SIZE - 1);
    int pos = atomicAdd(&hist[l], 1);
    csr[srs[l] + pos] = u >> BKT_SHIFT;
  }
  __syncthreads();
  for (int l = tid; l < nloc; l += 256) {
    int deg = hist[l];
    int pp = (deg + 7) & ~7;
    int s0 = srs[l];
    for (int q = s0 + deg; q < s0 + pp; ++q) csr[q] = N;  // sentinel: zero row
  }

  // x (fp32) -> xb_s (bf16, prescaled by dinv): 64 rows x 32 float4
  for (int i = tid; i < nloc * 32; i += 256) {
    const int l = i >> 5;
    const float dv = sdinv[l];
    float4 v = x4[(size_t)(node0 + l) * 32 + (i & 31)];
    ushort4 o;
    o.x = f2b(v.x * dv); o.y = f2b(v.y * dv);
    o.z = f2b(v.z * dv); o.w = f2b(v.w * dv);
    *(ushort4*)(xb + (size_t)(node0 + l) * D_IN + (i & 31) * 4) = o;
  }
}

// ========== K3: agg1 (Â x, prescaled) -> LDS A-tile -> gemm12 -> tb_s ==========
// Gather is weight-free (xb prescaled); A-tile value = dv * (self + sum).
// Epilogue stores tb_s[row] = dinv[row] * t[row] so agg2's gather is also free.

__global__ __launch_bounds__(512, 4) void agg1_gemm_kernel(
    const uint4* __restrict__ Hq, const int2* __restrict__ rowse,
    const int* __restrict__ csr, const float* __restrict__ dinv,
    const unsigned short* __restrict__ Wt1, const float* __restrict__ b1,
    const unsigned short* __restrict__ Wt2, unsigned short* __restrict__ T, int M) {
  __shared__ unsigned short as_[32][ASTR];  // Â x tile (bf16)
  __shared__ unsigned short hs[32][LSTR];   // h tile (bf16)
  const int tid = threadIdx.x;
  const int node0 = blockIdx.x * 32;

  // ---- agg phase: 32 nodes x 16 lanes ----
  {
    const int glane = tid & 15;
    const int lrow = tid >> 4;  // 0..31
    const int node = node0 + lrow;
    float acc[8] = {0.f, 0.f, 0.f, 0.f, 0.f, 0.f, 0.f, 0.f};
    float dv = 0.f;
    if (node < M) {
      dv = dinv[node];
      uint4 sv = Hq[(size_t)node * 16 + glane];  // self term: x_s[node]
      unpack8(sv, acc);
      gather_row(acc, Hq, csr, rowse[node], glane);
    }
    uint4 o;
    o.x = (unsigned)f2b(acc[0] * dv) | ((unsigned)f2b(acc[1] * dv) << 16);
    o.y = (unsigned)f2b(acc[2] * dv) | ((unsigned)f2b(acc[3] * dv) << 16);
    o.z = (unsigned)f2b(acc[4] * dv) | ((unsigned)f2b(acc[5] * dv) << 16);
    o.w = (unsigned)f2b(acc[6] * dv) | ((unsigned)f2b(acc[7] * dv) << 16);
    *(uint4*)&as_[lrow][glane * 8] = o;  // feature c at as_[row][c]
  }
  __syncthreads();

  // ---- gemm phase (8-wave column split) ----
  const int wave = tid >> 6;  // 0..7
  const int lane = tid & 63;
  const int quad = lane >> 4;
  const int l16 = lane & 15;

  // phase 1: hs[0..31][wave*32 .. +32) = relu(as_ @ W1 + b1)
  const short8* bp1 = (const short8*)(Wt1 + (size_t)(wave * 32 + l16) * D_IN + quad * 8);
  floatx4 acc1[2][2];  // [row-group][col-tile]
#pragma unroll
  for (int g = 0; g < 2; ++g)
#pragma unroll
    for (int t = 0; t < 2; ++t) acc1[g][t] = floatx4{0.f, 0.f, 0.f, 0.f};

#pragma unroll
  for (int kt = 0; kt < 4; ++kt) {  // K = 128
    short8 a0 = *(const short8*)&as_[0 * 16 + l16][kt * 32 + quad * 8];
    short8 a1 = *(const short8*)&as_[1 * 16 + l16][kt * 32 + quad * 8];
#pragma unroll
    for (int t = 0; t < 2; ++t) {
      short8 b = bp1[kt * 4 + t * 256];  // t*16 rows * 16 short8/row
      acc1[0][t] = __builtin_amdgcn_mfma_f32_16x16x32_bf16(a0, b, acc1[0][t], 0, 0, 0);
      acc1[1][t] = __builtin_amdgcn_mfma_f32_16x16x32_bf16(a1, b, acc1[1][t], 0, 0, 0);
    }
  }
#pragma unroll
  for (int t = 0; t < 2; ++t) {
    const float bv = b1[wave * 32 + t * 16 + l16];
#pragma unroll
    for (int g = 0; g < 2; ++g)
#pragma unroll
      for (int r = 0; r < 4; ++r) {
        float v = acc1[g][t][r] + bv;
        v = v > 0.f ? v : 0.f;
        hs[g * 16 + quad * 4 + r][wave * 32 + t * 16 + l16] = f2b(v);
      }
  }
  __syncthreads();

  // phase 2: t[0..31][wave*16 .. +16) = hs @ Wt2^T
  const short8* bp2 = (const short8*)(Wt2 + (size_t)(wave * 16 + l16) * HID + quad * 8);
  floatx4 acc2[2];
#pragma unroll
  for (int g = 0; g < 2; ++g) acc2[g] = floatx4{0.f, 0.f, 0.f, 0.f};

#pragma unroll
  for (int kt = 0; kt < 8; ++kt) {  // K = 256
    short8 a0 = *(const short8*)&hs[0 * 16 + l16][kt * 32 + quad * 8];
    short8 a1 = *(const short8*)&hs[1 * 16 + l16][kt * 32 + quad * 8];
    short8 b = bp2[kt * 4];
    acc2[0] = __builtin_amdgcn_mfma_f32_16x16x32_bf16(a0, b, acc2[0], 0, 0, 0);
    acc2[1] = __builtin_amdgcn_mfma_f32_16x16x32_bf16(a1, b, acc2[1], 0, 0, 0);
  }
  __syncthreads();  // all waves done reading hs before overwrite

  // t-tile -> LDS, PRESCALED: tb_s[row] = dinv[row] * t[row]
#pragma unroll
  for (int g = 0; g < 2; ++g)
#pragma unroll
    for (int r = 0; r < 4; ++r) {
      int rr = node0 + g * 16 + quad * 4 + r;
      float dvr = dinv[rr < M ? rr : M];  // dinv[M..N] valid; tail rows unstored
      hs[g * 16 + quad * 4 + r][wave * 16 + l16] = f2b(acc2[g][r] * dvr);
    }
  __syncthreads();

  // coalesced store: 32 rows x 128 cols bf16; 512 threads x 16B
  {
    const int r = tid >> 4;
    const int c = (tid & 15) * 8;
    const int row = node0 + r;
    uint4 v = *(const uint4*)&hs[r][c];
    if (row < M) *(uint4*)&T[(size_t)row * D_IN + c] = v;
  }
}

// ========== K4: agg2 (Â tb_s + skip + bias): weight-free gather, final *dv ==========

__global__ __launch_bounds__(256) void agg2_kernel(const uint4* __restrict__ Hq,
                                                   const int2* __restrict__ rowse,
                                                   const int* __restrict__ csr,
                                                   const float* __restrict__ dinv,
                                                   const float* __restrict__ skip,
                                                   const float* __restrict__ bias,
                                                   float* __restrict__ OUT, int n) {
  const int lane = threadIdx.x & 15;
  const int node = blockIdx.x * 16 + (threadIdx.x >> 4);
  if (node >= n) return;

  const float dv = dinv[node];
  float acc[8];
  {
    uint4 sv = Hq[(size_t)node * 16 + lane];  // self term: tb_s[node]
    unpack8(sv, acc);
  }
  gather_row(acc, Hq, csr, rowse[node], lane);

  const float* sp = skip + (size_t)node * 128 + lane * 8;
  const float* bp = bias + lane * 8;
  float4 s0 = *(const float4*)sp, s1 = *(const float4*)(sp + 4);
  float4 b0 = *(const float4*)bp, b1 = *(const float4*)(bp + 4);
  float* op = OUT + (size_t)node * 128 + lane * 8;
  *(float4*)op = make_float4(fmaf(acc[0], dv, s0.x + b0.x), fmaf(acc[1], dv, s0.y + b0.y),
                             fmaf(acc[2], dv, s0.z + b0.z), fmaf(acc[3], dv, s0.w + b0.w));
  *(float4*)(op + 4) = make_float4(fmaf(acc[4], dv, s1.x + b1.x), fmaf(acc[5], dv, s1.y + b1.y),
                                   fmaf(acc[6], dv, s1.z + b1.z), fmaf(acc[7], dv, s1.w + b1.w));
}

// ================= launch =================

extern "C" void kernel_launch(void* const* d_in, const int* in_sizes, int n_in,
                              void* d_out, int out_size, void* d_ws, size_t ws_size,
                              hipStream_t stream) {
  const float* x  = (const float*)d_in[0];
  const int*   ei = (const int*)d_in[1];
  const float* W1 = (const float*)d_in[2];
  const float* b1 = (const float*)d_in[3];
  const float* W2 = (const float*)d_in[4];
  const float* b2 = (const float*)d_in[5];
  float* out = (float*)d_out;

  const int N = in_sizes[0] / D_IN;      // requires N <= 65536 (packed ebuf)
  const int E = in_sizes[1] / 2;
  const int* srcA = ei;
  const int* dstA = ei + E;
  const int NBKT = (N + BKT_SIZE - 1) >> BKT_SHIFT;  // 782 for N=50000
  const int NCHUNK = (E + CHUNK - 1) / CHUNK;        // 391

  // ---- workspace (256B aligned) ----
  char* ws = (char*)d_ws;
  size_t off = 0;
  auto alloc = [&](size_t bytes) { void* p = ws + off; off = (off + bytes + 255) & ~(size_t)255; return p; };
  int*            bkt_cursor = (int*)           alloc((size_t)NBKT * 4);
  float*          dinv       = (float*)         alloc((size_t)(N + 1) * 4);  // +sentinel
  int2*           rowse      = (int2*)          alloc((size_t)N * 8);
  int*            ebuf       = (int*)           alloc((size_t)NBKT * BKT_CAP * 4);
  int*            csr        = (int*)           alloc((size_t)NBKT * (BKT_CAP + PAD_SLACK) * 4);
  unsigned short* xb         = (unsigned short*)alloc((size_t)(N + 1) * D_IN * 2);
  unsigned short* tb         = (unsigned short*)alloc((size_t)(N + 1) * D_IN * 2);
  unsigned short* Wt1        = (unsigned short*)alloc((size_t)D_IN * HID * 2);
  unsigned short* Wt2        = (unsigned short*)alloc((size_t)D_IN * HID * 2);

  // 1) zero relative bucket cursors
  (void)hipMemsetAsync(bkt_cursor, 0, (size_t)NBKT * 4, stream);
  // 2) K1: bin_scatter + W transposes + sentinels (x conversion moved to build)
  fused_front_kernel<<<NCHUNK + 256 + 1, 256, 0, stream>>>(
      srcA, dstA, bkt_cursor, ebuf, E, NBKT, NCHUNK,
      W1, Wt1, W2, Wt2, dinv, xb, tb, N);
  // 3) K2: per-bucket build + prescaled x->xb conversion (782 blocks)
  bucket_build_kernel<<<NBKT, 256, 0, stream>>>(ebuf, bkt_cursor, (const float4*)x,
                                                xb, dinv, rowse, csr, N, NBKT);
  // 4) K3: tb_s = dinv * (relu((Â x) @ W1 + b1) @ W2)
  agg1_gemm_kernel<<<(N + 31) / 32, 512, 0, stream>>>((const uint4*)xb, rowse, csr, dinv,
                                                      Wt1, b1, Wt2, tb, N);
  // 5) K4: out = Â tb + x + b2   (gather of prescaled tb_s, final *dv)
  agg2_kernel<<<(N + 15) / 16, 256, 0, stream>>>((const uint4*)tb, rowse, csr,
                                                 dinv, x, b2, out, N);
}